// Round 3
// baseline (1200.608 us; speedup 1.0000x reference)
//
#include <hip/hip_runtime.h>

// 2-stage fused pipeline for the windowed-attention decoder block (one
// 64-token window per workgroup, 512 thr).
// __launch_bounds__(512,2): min blocks/CU (CUDA semantics) -> VGPR cap 128.
// K_A LDS cut to 68 KB (was 80 KB): at 80 KB only ONE block/CU was resident
// (occupancy 24% measured; 2x81920 = exactly 160 KiB never co-schedules).
// 68 KB x 2 = 136 KB < 160 KiB -> 2 blocks/CU.
//   K_A: x -> GEMM1+LN+GELU -> h(LDS) -> GEMM2(qkv) -> window attn -> ao (bf16 global)
//   K_B: ao -> GEMM3+LN+GELU -> h2(LDS) -> GEMM4 -> out (f32)
// K_A LDS schedule:
//   [0,64K)   rA/rB: x-tile -> h (gemmT output) -> after S2: qk overlay
//             one SHIFT at a time in [0,32K) (4 heads x 8K q|k; P overlays)
//   [32K,64K) after S2: vt for BOTH shifts (2 x 4 heads x 4K)
//   [64K,68K) LN partials (dead after gemmT)
// Waves 4-7 hold qreg/kreg in registers through shift 0 and stage them at the
// inter-shift barrier (vt is staged up-front from vreg by all waves at S2).

typedef __bf16 bf16_t;
typedef __bf16 bf16x8 __attribute__((ext_vector_type(8)));
typedef __bf16 bf16x4 __attribute__((ext_vector_type(4)));
typedef float f32x4 __attribute__((ext_vector_type(4)));

__device__ __forceinline__ f32x4 mfma16(bf16x8 a, bf16x8 b, f32x4 acc) {
  return __builtin_amdgcn_mfma_f32_16x16x32_bf16(a, b, acc, 0, 0, 0);
}

// XOR-swizzle: fold row's low 3 bits into byte-address bits [6:4].
#define SWZ(row, byteoff) ((byteoff) ^ (((row) & 7) << 4))

// cheap GELU: tanh form, max |err| vs exact erf-GELU ~3e-4.
__device__ __forceinline__ float gelu_f(float v) {
  float e = __expf(v * (1.59576912f + 0.07135482f * v * v));
  return v - v * __builtin_amdgcn_rcpf(1.0f + e);
}

// transpose + convert: dst[n*K + k] = bf16(src[k*N + n])
__global__ void wtrans_kernel(const float* __restrict__ src, bf16_t* __restrict__ dst,
                              int kshift, int N, int total) {
  int i = blockIdx.x * 256 + threadIdx.x;
  if (i >= total) return;
  int K = 1 << kshift;
  int k = i & (K - 1);
  int n = i >> kshift;
  dst[i] = (bf16_t)src[(size_t)k * N + n];
}

// expand rpb[(2*8-1)^2][8] -> bt[8][64][64] f32 (window-invariant)
__global__ void biastab_kernel(const float* __restrict__ rpb, float* __restrict__ bt) {
  int e = blockIdx.x * 256 + threadIdx.x;  // 32768 total
  int hd = e >> 12, i = (e >> 6) & 63, j = e & 63;
  int idx = ((i >> 3) - (j >> 3) + 7) * 15 + ((i & 7) - (j & 7) + 7);
  bt[e] = rpb[idx * 8 + hd];
}

// Transposed GEMM (C^T = W * A^T) + bias + LayerNorm(512) + cheap GELU.
// bsrc: [64 tok][256 k] bf16 LDS tile (swizzled, 512 B rows).
// wt:   [512 feat][256 k] bf16 global. Output staged to h-halves in LDS.
// Contains ONE __syncthreads.
__device__ __forceinline__ void gemmT_ln_gelu(
    const char* bsrc, const bf16_t* __restrict__ wt,
    const float* __restrict__ bias, const float* __restrict__ gamma,
    const float* __restrict__ beta,
    char* dst, int flb, float2* part, int wave, int g, int c)
{
  f32x4 acc[4][4] = {};
#pragma unroll
  for (int kt = 0; kt < 8; ++kt) {
    bf16x8 a[4], b[4];
#pragma unroll
    for (int mt = 0; mt < 4; ++mt)
      a[mt] = *(const bf16x8*)(wt + (size_t)(wave * 64 + mt * 16 + c) * 256 + kt * 32 + g * 8);
#pragma unroll
    for (int nt = 0; nt < 4; ++nt) {
      int T = nt * 16 + c;
      b[nt] = *(const bf16x8*)(bsrc + SWZ(T, T * 512 + kt * 64 + g * 16));
    }
#pragma unroll
    for (int mt = 0; mt < 4; ++mt)
#pragma unroll
      for (int nt = 0; nt < 4; ++nt)
        acc[mt][nt] = mfma16(a[mt], b[nt], acc[mt][nt]);
  }
  float s[4] = {0.f, 0.f, 0.f, 0.f}, ss[4] = {0.f, 0.f, 0.f, 0.f};
#pragma unroll
  for (int mt = 0; mt < 4; ++mt) {
    float4 b4 = *(const float4*)(bias + wave * 64 + mt * 16 + g * 4);
#pragma unroll
    for (int nt = 0; nt < 4; ++nt)
#pragma unroll
      for (int r = 0; r < 4; ++r) {
        float v = acc[mt][nt][r] + ((const float*)&b4)[r];
        acc[mt][nt][r] = v;
        s[nt] += v;
        ss[nt] += v * v;
      }
  }
#pragma unroll
  for (int nt = 0; nt < 4; ++nt) {
    float sv = s[nt], ssv = ss[nt];
    sv += __shfl_xor(sv, 16, 64); ssv += __shfl_xor(ssv, 16, 64);
    sv += __shfl_xor(sv, 32, 64); ssv += __shfl_xor(ssv, 32, 64);
    if (g == 0) part[wave * 64 + nt * 16 + c] = make_float2(sv, ssv);
  }
  __syncthreads();
#pragma unroll
  for (int nt = 0; nt < 4; ++nt) {
    float sv = 0.f, ssv = 0.f;
#pragma unroll
    for (int w = 0; w < 8; ++w) {
      float2 p2 = part[w * 64 + nt * 16 + c];
      sv += p2.x; ssv += p2.y;
    }
    float m = sv * (1.f / 512.f);
    float rstd = rsqrtf(ssv * (1.f / 512.f) - m * m + 1e-5f);
#pragma unroll
    for (int mt = 0; mt < 4; ++mt)
#pragma unroll
      for (int r = 0; r < 4; ++r)
        acc[mt][nt][r] = (acc[mt][nt][r] - m) * rstd;
  }
#pragma unroll
  for (int mt = 0; mt < 4; ++mt) {
    float4 g4 = *(const float4*)(gamma + wave * 64 + mt * 16 + g * 4);
    float4 be4 = *(const float4*)(beta + wave * 64 + mt * 16 + g * 4);
    int f0 = flb + mt * 16 + g * 4;
#pragma unroll
    for (int nt = 0; nt < 4; ++nt) {
      int T = nt * 16 + c;
      bf16x4 h4;
#pragma unroll
      for (int r = 0; r < 4; ++r) {
        float v = acc[mt][nt][r] * ((const float*)&g4)[r] + ((const float*)&be4)[r];
        h4[r] = (bf16_t)gelu_f(v);
      }
      *(bf16x4*)(dst + SWZ(T, T * 512 + f0 * 2)) = h4;
    }
  }
}

// ========== K_A: x -> GEMM1+LN+GELU -> h(LDS) -> GEMM2 -> attn -> ao ==========
__global__ __launch_bounds__(512, 2) void g1qa_kernel(
    const float* __restrict__ x,
    const bf16_t* __restrict__ w1t, const float* __restrict__ b1,
    const float* __restrict__ gamma1, const float* __restrict__ beta1,
    const bf16_t* __restrict__ w2t, const float* __restrict__ b2,
    const float* __restrict__ bt,
    bf16_t* __restrict__ ao)
{
  __shared__ __align__(16) char sm[69632];
  char* rA = sm;
  char* rB = sm + 32768;
  float2* part = (float2*)(sm + 65536);
  const int tid = threadIdx.x;
  const int wave = tid >> 6, lane = tid & 63;
  const int g = lane >> 4, c = lane & 15;
  const int win = blockIdx.x;
  const int head = wave;

  // ---- stage x (f32 -> bf16 tile, coalesced) ----
  const float* xw = x + (size_t)win * 16384;
#pragma unroll
  for (int it = 0; it < 8; ++it) {
    int e = it * 2048 + tid * 4;
    float4 v = *(const float4*)(xw + e);
    int row = e >> 8, col = e & 255;
    bf16x4 t4;
    t4[0] = (bf16_t)v.x; t4[1] = (bf16_t)v.y; t4[2] = (bf16_t)v.z; t4[3] = (bf16_t)v.w;
    *(bf16x4*)(rA + SWZ(row, row * 512 + col * 2)) = t4;
  }
  __syncthreads();
  gemmT_ln_gelu(rA, w1t, b1, gamma1, beta1, (wave < 4) ? rB : rA, (wave & 3) * 64,
                part, wave, g, c);
  __syncthreads();  // S1: h complete (rB = feats 0-255, rA = feats 256-511)

  bf16x4 vreg[2][4], qreg[2][4], kreg[2][4];

  // ---- G2 round v (ALL waves keep result in vreg) ----
  {
    f32x4 acc[2][4] = {};
#pragma unroll
    for (int kt = 0; kt < 16; ++kt) {
      const char* hb = (kt < 8) ? rB : rA;
      const int ko = (kt & 7) * 64 + g * 16;
      bf16x8 a[2], b[4];
#pragma unroll
      for (int mt = 0; mt < 2; ++mt)
        a[mt] = *(const bf16x8*)(w2t + (size_t)(512 + head * 32 + mt * 16 + c) * 512 + kt * 32 + g * 8);
#pragma unroll
      for (int nt = 0; nt < 4; ++nt) {
        int T = nt * 16 + c;
        b[nt] = *(const bf16x8*)(hb + SWZ(T, T * 512 + ko));
      }
#pragma unroll
      for (int mt = 0; mt < 2; ++mt)
#pragma unroll
        for (int nt = 0; nt < 4; ++nt)
          acc[mt][nt] = mfma16(a[mt], b[nt], acc[mt][nt]);
    }
#pragma unroll
    for (int mt = 0; mt < 2; ++mt) {
      float4 b4 = *(const float4*)(b2 + 512 + head * 32 + mt * 16 + g * 4);
#pragma unroll
      for (int nt = 0; nt < 4; ++nt) {
        bf16x4 o4;
#pragma unroll
        for (int r = 0; r < 4; ++r)
          o4[r] = (bf16_t)(acc[mt][nt][r] + ((const float*)&b4)[r]);
        vreg[mt][nt] = o4;
      }
    }
  }
  // ---- G2 round q (scaled) ----
  {
    f32x4 acc[2][4] = {};
#pragma unroll
    for (int kt = 0; kt < 16; ++kt) {
      const char* hb = (kt < 8) ? rB : rA;
      const int ko = (kt & 7) * 64 + g * 16;
      bf16x8 a[2], b[4];
#pragma unroll
      for (int mt = 0; mt < 2; ++mt)
        a[mt] = *(const bf16x8*)(w2t + (size_t)(head * 32 + mt * 16 + c) * 512 + kt * 32 + g * 8);
#pragma unroll
      for (int nt = 0; nt < 4; ++nt) {
        int T = nt * 16 + c;
        b[nt] = *(const bf16x8*)(hb + SWZ(T, T * 512 + ko));
      }
#pragma unroll
      for (int mt = 0; mt < 2; ++mt)
#pragma unroll
        for (int nt = 0; nt < 4; ++nt)
          acc[mt][nt] = mfma16(a[mt], b[nt], acc[mt][nt]);
    }
#pragma unroll
    for (int mt = 0; mt < 2; ++mt) {
      float4 b4 = *(const float4*)(b2 + head * 32 + mt * 16 + g * 4);
#pragma unroll
      for (int nt = 0; nt < 4; ++nt) {
        bf16x4 o4;
#pragma unroll
        for (int r = 0; r < 4; ++r)
          o4[r] = (bf16_t)((acc[mt][nt][r] + ((const float*)&b4)[r]) * 0.17677669529663687f);
        qreg[mt][nt] = o4;
      }
    }
  }
  // ---- G2 round k ----
  {
    f32x4 acc[2][4] = {};
#pragma unroll
    for (int kt = 0; kt < 16; ++kt) {
      const char* hb = (kt < 8) ? rB : rA;
      const int ko = (kt & 7) * 64 + g * 16;
      bf16x8 a[2], b[4];
#pragma unroll
      for (int mt = 0; mt < 2; ++mt)
        a[mt] = *(const bf16x8*)(w2t + (size_t)(256 + head * 32 + mt * 16 + c) * 512 + kt * 32 + g * 8);
#pragma unroll
      for (int nt = 0; nt < 4; ++nt) {
        int T = nt * 16 + c;
        b[nt] = *(const bf16x8*)(hb + SWZ(T, T * 512 + ko));
      }
#pragma unroll
      for (int mt = 0; mt < 2; ++mt)
#pragma unroll
        for (int nt = 0; nt < 4; ++nt)
          acc[mt][nt] = mfma16(a[mt], b[nt], acc[mt][nt]);
    }
#pragma unroll
    for (int mt = 0; mt < 2; ++mt) {
      float4 b4 = *(const float4*)(b2 + 256 + head * 32 + mt * 16 + g * 4);
#pragma unroll
      for (int nt = 0; nt < 4; ++nt) {
        bf16x4 o4;
#pragma unroll
        for (int r = 0; r < 4; ++r)
          o4[r] = (bf16_t)(acc[mt][nt][r] + ((const float*)&b4)[r]);
        kreg[mt][nt] = o4;
      }
    }
  }
  __syncthreads();  // S2: all h reads done -> [0,64K) reusable

  // ---- stage vt for BOTH shifts into [32K,64K); waves 0-3 stage qk0 ----
  {
    char* vs = sm + 32768 + (head >> 2) * 16384 + (head & 3) * 4096;
#pragma unroll
    for (int mt = 0; mt < 2; ++mt)
#pragma unroll
      for (int nt = 0; nt < 4; ++nt) {
        int T = nt * 16 + c;
#pragma unroll
        for (int r = 0; r < 4; ++r) {
          int d = mt * 16 + g * 4 + r;
          *(bf16_t*)(vs + SWZ(d, d * 128 + T * 2)) = vreg[mt][nt][r];
        }
      }
  }
  if (head < 4) {
    char* qb = sm + head * 8192;
#pragma unroll
    for (int mt = 0; mt < 2; ++mt)
#pragma unroll
      for (int nt = 0; nt < 4; ++nt) {
        int T = nt * 16 + c, d0 = mt * 16 + g * 4;
        *(bf16x4*)(qb + SWZ(T, T * 64 + d0 * 2)) = qreg[mt][nt];
        *(bf16x4*)(qb + 4096 + SWZ(T, T * 64 + d0 * 2)) = kreg[mt][nt];
      }
  }

  // ---- attention: 2 shifts; pair (wave, wave^4) splits each head's rows ----
  const int rowbase = (wave >> 2) * 32;
#pragma unroll
  for (int s = 0; s < 2; ++s) {
    if (s == 1 && head >= 4) {  // stage qk1 from held regs (qb region now dead)
      char* qb = sm + (head & 3) * 8192;
#pragma unroll
      for (int mt = 0; mt < 2; ++mt)
#pragma unroll
        for (int nt = 0; nt < 4; ++nt) {
          int T = nt * 16 + c, d0 = mt * 16 + g * 4;
          *(bf16x4*)(qb + SWZ(T, T * 64 + d0 * 2)) = qreg[mt][nt];
          *(bf16x4*)(qb + 4096 + SWZ(T, T * 64 + d0 * 2)) = kreg[mt][nt];
        }
    }
    __syncthreads();  // staged q/k/vt visible

    const int hd = s * 4 + (wave & 3);
    char* qb = sm + (wave & 3) * 8192;
    char* vslot = sm + 32768 + s * 16384 + (wave & 3) * 4096;
    const float* btab = bt + hd * 4096;  // [64][64] f32

    bf16x8 aq[2], bk[4];
#pragma unroll
    for (int mt = 0; mt < 2; ++mt) {
      int t = rowbase + mt * 16 + c;
      aq[mt] = *(const bf16x8*)(qb + SWZ(t, t * 64 + g * 16));
    }
#pragma unroll
    for (int nt = 0; nt < 4; ++nt) {
      int t = nt * 16 + c;
      bk[nt] = *(const bf16x8*)(qb + 4096 + SWZ(t, t * 64 + g * 16));
    }
    float p[2][4][4];
#pragma unroll
    for (int mt = 0; mt < 2; ++mt)
#pragma unroll
      for (int nt = 0; nt < 4; ++nt) {
        f32x4 z = {0.f, 0.f, 0.f, 0.f};
        f32x4 s4 = mfma16(aq[mt], bk[nt], z);
#pragma unroll
        for (int r = 0; r < 4; ++r) {
          int i = rowbase + mt * 16 + g * 4 + r, j = nt * 16 + c;
          p[mt][nt][r] = s4[r] + btab[i * 64 + j];
        }
      }
#pragma unroll
    for (int mt = 0; mt < 2; ++mt)
#pragma unroll
      for (int r = 0; r < 4; ++r) {
        float mx = fmaxf(fmaxf(p[mt][0][r], p[mt][1][r]), fmaxf(p[mt][2][r], p[mt][3][r]));
#pragma unroll
        for (int m = 1; m < 16; m <<= 1) mx = fmaxf(mx, __shfl_xor(mx, m, 64));
        float sum = 0.f;
#pragma unroll
        for (int nt = 0; nt < 4; ++nt) {
          float e = __expf(p[mt][nt][r] - mx);
          p[mt][nt][r] = e; sum += e;
        }
#pragma unroll
        for (int m = 1; m < 16; m <<= 1) sum += __shfl_xor(sum, m, 64);
        float rinv = 1.f / sum;
#pragma unroll
        for (int nt = 0; nt < 4; ++nt) p[mt][nt][r] *= rinv;
      }
    __syncthreads();  // pair's q/k reads done before P overlays them
#pragma unroll
    for (int mt = 0; mt < 2; ++mt)
#pragma unroll
      for (int nt = 0; nt < 4; ++nt)
#pragma unroll
        for (int r = 0; r < 4; ++r) {
          int i = rowbase + mt * 16 + g * 4 + r, j = nt * 16 + c;
          *(bf16_t*)(qb + SWZ(i, i * 128 + j * 2)) = (bf16_t)p[mt][nt][r];
        }
    asm volatile("s_waitcnt lgkmcnt(0)" ::: "memory");  // in-wave P write->read
    f32x4 oacc[2][2] = {};
#pragma unroll
    for (int kp = 0; kp < 2; ++kp) {
      bf16x8 ap[2], bv[2];
#pragma unroll
      for (int mt = 0; mt < 2; ++mt) {
        int t = rowbase + mt * 16 + c;
        ap[mt] = *(const bf16x8*)(qb + SWZ(t, t * 128 + kp * 64 + g * 16));
      }
#pragma unroll
      for (int nt = 0; nt < 2; ++nt) {
        int d = nt * 16 + c;
        bv[nt] = *(const bf16x8*)(vslot + SWZ(d, d * 128 + kp * 64 + g * 16));
      }
#pragma unroll
      for (int mt = 0; mt < 2; ++mt)
#pragma unroll
        for (int nt = 0; nt < 2; ++nt)
          oacc[mt][nt] = mfma16(ap[mt], bv[nt], oacc[mt][nt]);
    }
#pragma unroll
    for (int mt = 0; mt < 2; ++mt)
#pragma unroll
      for (int nt = 0; nt < 2; ++nt)
#pragma unroll
        for (int r = 0; r < 4; ++r) {
          int T = rowbase + mt * 16 + g * 4 + r;
          ao[(size_t)(win * 64 + T) * 256 + hd * 32 + nt * 16 + c] = (bf16_t)oacc[mt][nt][r];
        }
    if (s == 0) __syncthreads();  // P/vslot reads done before qk1 staging
  }
}

// ========== K_B: ao -> GEMM3+LN+GELU -> h2(LDS) -> GEMM4 -> out ==========
__global__ __launch_bounds__(512, 2) void g3g4_kernel(
    const bf16_t* __restrict__ ao,
    const bf16_t* __restrict__ wp1t, const float* __restrict__ bp1,
    const float* __restrict__ gp, const float* __restrict__ bep,
    const bf16_t* __restrict__ wp2t, const float* __restrict__ bp2,
    float* __restrict__ out)
{
  __shared__ __align__(16) char sm[69632];
  char* rA = sm;
  char* rB = sm + 32768;
  float2* part = (float2*)(sm + 65536);
  const int tid = threadIdx.x;
  const int wave = tid >> 6, lane = tid & 63;
  const int g = lane >> 4, c = lane & 15;
  const int win = blockIdx.x;

  // ---- stage ao (coalesced) ----
  const bf16_t* aow = ao + (size_t)win * 16384;
#pragma unroll
  for (int it = 0; it < 4; ++it) {
    int e = it * 4096 + tid * 8;
    bf16x8 v = *(const bf16x8*)(aow + e);
    int row = e >> 8, col = e & 255;
    *(bf16x8*)(rA + SWZ(row, row * 512 + col * 2)) = v;
  }
  __syncthreads();
  gemmT_ln_gelu(rA, wp1t, bp1, gp, bep, (wave < 4) ? rB : rA, (wave & 3) * 64,
                part, wave, g, c);
  __syncthreads();  // h2 complete (rB = feats 0-255, rA = feats 256-511)

  // ---- GEMM4: out = h2 @ wp2 + bp2 ----
  f32x4 acc[2][4] = {};
#pragma unroll
  for (int kt = 0; kt < 16; ++kt) {
    const char* hb = (kt < 8) ? rB : rA;
    const int ko = (kt & 7) * 64 + g * 16;
    bf16x8 a[2], b[4];
#pragma unroll
    for (int mt = 0; mt < 2; ++mt)
      a[mt] = *(const bf16x8*)(wp2t + (size_t)(wave * 32 + mt * 16 + c) * 512 + kt * 32 + g * 8);
#pragma unroll
    for (int nt = 0; nt < 4; ++nt) {
      int T = nt * 16 + c;
      b[nt] = *(const bf16x8*)(hb + SWZ(T, T * 512 + ko));
    }
#pragma unroll
    for (int mt = 0; mt < 2; ++mt)
#pragma unroll
      for (int nt = 0; nt < 4; ++nt)
        acc[mt][nt] = mfma16(a[mt], b[nt], acc[mt][nt]);
  }
  float* ow = out + (size_t)win * 16384;
#pragma unroll
  for (int mt = 0; mt < 2; ++mt) {
    float4 b4 = *(const float4*)(bp2 + wave * 32 + mt * 16 + g * 4);
#pragma unroll
    for (int nt = 0; nt < 4; ++nt) {
      int T = nt * 16 + c;
      f32x4 o4;
#pragma unroll
      for (int r = 0; r < 4; ++r) o4[r] = acc[mt][nt][r] + ((const float*)&b4)[r];
      *(f32x4*)(ow + T * 256 + wave * 32 + mt * 16 + g * 4) = o4;
    }
  }
}

extern "C" void kernel_launch(void* const* d_in, const int* in_sizes, int n_in,
                              void* d_out, int out_size, void* d_ws, size_t ws_size,
                              hipStream_t stream) {
  const float* x   = (const float*)d_in[0];
  const float* w1  = (const float*)d_in[1];
  const float* b1  = (const float*)d_in[2];
  const float* g1  = (const float*)d_in[3];
  const float* be1 = (const float*)d_in[4];
  const float* w2  = (const float*)d_in[5];
  const float* b2  = (const float*)d_in[6];
  const float* rpb = (const float*)d_in[7];
  const float* wp1 = (const float*)d_in[8];
  const float* bp1 = (const float*)d_in[9];
  const float* gp  = (const float*)d_in[10];
  const float* bep = (const float*)d_in[11];
  const float* wp2 = (const float*)d_in[12];
  const float* bp2 = (const float*)d_in[13];
  float* out = (float*)d_out;
  char* ws = (char*)d_ws;
  // ws layout: transposed bf16 weights (1.5 MB) | bias table (128 KB) | ao (128 MB)
  bf16_t* w1t  = (bf16_t*)(ws + 0);          // [512][256]
  bf16_t* w2t  = (bf16_t*)(ws + 262144);     // [768][512]
  bf16_t* wp1t = (bf16_t*)(ws + 1048576);    // [512][256]
  bf16_t* wp2t = (bf16_t*)(ws + 1310720);    // [256][512]
  float*  bt   = (float*)(ws + 1572864);     // [8][64][64] f32
  bf16_t* ao   = (bf16_t*)(ws + 2097152);    // [262144][256] bf16 = 128 MB

  wtrans_kernel<<<512, 256, 0, stream>>>(w1, w1t, 8, 512, 131072);
  wtrans_kernel<<<1536, 256, 0, stream>>>(w2, w2t, 9, 768, 393216);
  wtrans_kernel<<<512, 256, 0, stream>>>(wp1, wp1t, 8, 512, 131072);
  wtrans_kernel<<<512, 256, 0, stream>>>(wp2, wp2t, 9, 256, 131072);
  biastab_kernel<<<128, 256, 0, stream>>>(rpb, bt);

  g1qa_kernel<<<4096, 512, 0, stream>>>(x, w1t, b1, g1, be1, w2t, b2, bt, ao);
  g3g4_kernel<<<4096, 512, 0, stream>>>(ao, wp1t, bp1, gp, bep, wp2t, bp2, out);
}

// Round 4
// 1123.952 us; speedup vs baseline: 1.0682x; 1.0682x over previous
//
#include <hip/hip_runtime.h>

// 2-stage fused pipeline, ONE 64-token window per 1024-thread block (16 waves).
// Measured rounds 0-3: residency is ~1 block/CU regardless of LDS (68-80KB)
// at VGPR=128 -> put 16 waves in the one resident block instead of 8, halve
// per-wave tiles (less register pressure, no spills), and collapse the
// attention 2-shift loop into one pass (16 waves = 8 heads x 2 row-halves).
//   K_A: x -> GEMM1+LN+GELU -> h(LDS) -> GEMM2(qkv) -> window attn -> ao (bf16)
//   K_B: ao -> GEMM3+LN+GELU -> h2(LDS) -> GEMM4 -> out (f32)
// K_A LDS (96 KB):
//   [0,64K)   rA/rB: x-tile -> h -> (after S2) qk slots, 8 heads x 8K (q|k),
//             P overlays qk per head during PV
//   [64K,96K) vt 8 heads x 4K (staged after S2); LN partials early (dead by S2)
// K_B LDS (72 KB): [0,64K) tile/h2 halves, [64K,72K) LN partials.

typedef __bf16 bf16_t;
typedef __bf16 bf16x8 __attribute__((ext_vector_type(8)));
typedef __bf16 bf16x4 __attribute__((ext_vector_type(4)));
typedef float f32x4 __attribute__((ext_vector_type(4)));

__device__ __forceinline__ f32x4 mfma16(bf16x8 a, bf16x8 b, f32x4 acc) {
  return __builtin_amdgcn_mfma_f32_16x16x32_bf16(a, b, acc, 0, 0, 0);
}

// XOR-swizzle: fold row's low 3 bits into byte-address bits [6:4].
#define SWZ(row, byteoff) ((byteoff) ^ (((row) & 7) << 4))

// cheap GELU: tanh form, max |err| vs exact erf-GELU ~3e-4.
__device__ __forceinline__ float gelu_f(float v) {
  float e = __expf(v * (1.59576912f + 0.07135482f * v * v));
  return v - v * __builtin_amdgcn_rcpf(1.0f + e);
}

// transpose + convert: dst[n*K + k] = bf16(src[k*N + n])
__global__ void wtrans_kernel(const float* __restrict__ src, bf16_t* __restrict__ dst,
                              int kshift, int N, int total) {
  int i = blockIdx.x * 256 + threadIdx.x;
  if (i >= total) return;
  int K = 1 << kshift;
  int k = i & (K - 1);
  int n = i >> kshift;
  dst[i] = (bf16_t)src[(size_t)k * N + n];
}

// expand rpb[(2*8-1)^2][8] -> bt[8][64][64] f32 (window-invariant)
__global__ void biastab_kernel(const float* __restrict__ rpb, float* __restrict__ bt) {
  int e = blockIdx.x * 256 + threadIdx.x;  // 32768 total
  int hd = e >> 12, i = (e >> 6) & 63, j = e & 63;
  int idx = ((i >> 3) - (j >> 3) + 7) * 15 + ((i & 7) - (j & 7) + 7);
  bt[e] = rpb[idx * 8 + hd];
}

// 16-wave transposed GEMM (C^T = W * A^T) + bias + LayerNorm(512) + cheap GELU.
// Each wave produces 32 output features. bsrc: [64 tok][256 k] bf16 LDS tile
// (swizzled, 512 B rows). wt: [512 feat][256 k] bf16 global.
// Output staged to h-halves in LDS. Contains ONE __syncthreads.
__device__ __forceinline__ void gemmT_ln_gelu16(
    const char* bsrc, const bf16_t* __restrict__ wt,
    const float* __restrict__ bias, const float* __restrict__ gamma,
    const float* __restrict__ beta,
    char* dst, int flb, float2* part, int wave, int g, int c)
{
  f32x4 acc[2][4] = {};
#pragma unroll
  for (int kt = 0; kt < 8; ++kt) {
    bf16x8 a[2], b[4];
#pragma unroll
    for (int mt = 0; mt < 2; ++mt)
      a[mt] = *(const bf16x8*)(wt + (size_t)(wave * 32 + mt * 16 + c) * 256 + kt * 32 + g * 8);
#pragma unroll
    for (int nt = 0; nt < 4; ++nt) {
      int T = nt * 16 + c;
      b[nt] = *(const bf16x8*)(bsrc + SWZ(T, T * 512 + kt * 64 + g * 16));
    }
#pragma unroll
    for (int mt = 0; mt < 2; ++mt)
#pragma unroll
      for (int nt = 0; nt < 4; ++nt)
        acc[mt][nt] = mfma16(a[mt], b[nt], acc[mt][nt]);
  }
  float s[4] = {0.f, 0.f, 0.f, 0.f}, ss[4] = {0.f, 0.f, 0.f, 0.f};
#pragma unroll
  for (int mt = 0; mt < 2; ++mt) {
    float4 b4 = *(const float4*)(bias + wave * 32 + mt * 16 + g * 4);
#pragma unroll
    for (int nt = 0; nt < 4; ++nt)
#pragma unroll
      for (int r = 0; r < 4; ++r) {
        float v = acc[mt][nt][r] + ((const float*)&b4)[r];
        acc[mt][nt][r] = v;
        s[nt] += v;
        ss[nt] += v * v;
      }
  }
#pragma unroll
  for (int nt = 0; nt < 4; ++nt) {
    float sv = s[nt], ssv = ss[nt];
    sv += __shfl_xor(sv, 16, 64); ssv += __shfl_xor(ssv, 16, 64);
    sv += __shfl_xor(sv, 32, 64); ssv += __shfl_xor(ssv, 32, 64);
    if (g == 0) part[wave * 64 + nt * 16 + c] = make_float2(sv, ssv);
  }
  __syncthreads();
#pragma unroll
  for (int nt = 0; nt < 4; ++nt) {
    float sv = 0.f, ssv = 0.f;
#pragma unroll
    for (int w = 0; w < 16; ++w) {
      float2 p2 = part[w * 64 + nt * 16 + c];
      sv += p2.x; ssv += p2.y;
    }
    float m = sv * (1.f / 512.f);
    float rstd = rsqrtf(ssv * (1.f / 512.f) - m * m + 1e-5f);
#pragma unroll
    for (int mt = 0; mt < 2; ++mt)
#pragma unroll
      for (int r = 0; r < 4; ++r)
        acc[mt][nt][r] = (acc[mt][nt][r] - m) * rstd;
  }
#pragma unroll
  for (int mt = 0; mt < 2; ++mt) {
    float4 g4 = *(const float4*)(gamma + wave * 32 + mt * 16 + g * 4);
    float4 be4 = *(const float4*)(beta + wave * 32 + mt * 16 + g * 4);
    int f0 = flb + mt * 16 + g * 4;
#pragma unroll
    for (int nt = 0; nt < 4; ++nt) {
      int T = nt * 16 + c;
      bf16x4 h4;
#pragma unroll
      for (int r = 0; r < 4; ++r) {
        float v = acc[mt][nt][r] * ((const float*)&g4)[r] + ((const float*)&be4)[r];
        h4[r] = (bf16_t)gelu_f(v);
      }
      *(bf16x4*)(dst + SWZ(T, T * 512 + f0 * 2)) = h4;
    }
  }
}

// ========== K_A: x -> GEMM1+LN+GELU -> h(LDS) -> GEMM2 -> attn -> ao ==========
__global__ __launch_bounds__(1024, 1) void g1qa_kernel(
    const float* __restrict__ x,
    const bf16_t* __restrict__ w1t, const float* __restrict__ b1,
    const float* __restrict__ gamma1, const float* __restrict__ beta1,
    const bf16_t* __restrict__ w2t, const float* __restrict__ b2,
    const float* __restrict__ bt,
    bf16_t* __restrict__ ao)
{
  __shared__ __align__(16) char sm[98304];
  char* rA = sm;
  char* rB = sm + 32768;
  float2* part = (float2*)(sm + 65536);  // dead before vt is staged (2 barriers apart)
  const int tid = threadIdx.x;
  const int wave = tid >> 6, lane = tid & 63;
  const int g = lane >> 4, c = lane & 15;
  const int win = blockIdx.x;

  // ---- stage x (f32 -> bf16 tile, coalesced) ----
  const float* xw = x + (size_t)win * 16384;
#pragma unroll
  for (int it = 0; it < 4; ++it) {
    int e = it * 4096 + tid * 4;
    float4 v = *(const float4*)(xw + e);
    int row = e >> 8, col = e & 255;
    bf16x4 t4;
    t4[0] = (bf16_t)v.x; t4[1] = (bf16_t)v.y; t4[2] = (bf16_t)v.z; t4[3] = (bf16_t)v.w;
    *(bf16x4*)(rA + SWZ(row, row * 512 + col * 2)) = t4;
  }
  __syncthreads();
  gemmT_ln_gelu16(rA, w1t, b1, gamma1, beta1, (wave < 8) ? rB : rA, (wave & 7) * 32,
                  part, wave, g, c);
  __syncthreads();  // S1: h complete (rB = feats 0-255, rA = feats 256-511)

  // ---- G2: 16 waves = 8 heads x 2 feat-halves; rounds v, q, k to registers ----
  const int hh = wave >> 1, mh = wave & 1;
  bf16x4 vreg[4], qreg[4], kreg[4];
  // round v
  {
    f32x4 acc[4] = {};
#pragma unroll
    for (int kt = 0; kt < 16; ++kt) {
      const char* hb = (kt < 8) ? rB : rA;
      const int ko = (kt & 7) * 64 + g * 16;
      bf16x8 a = *(const bf16x8*)(w2t + (size_t)(512 + hh * 32 + mh * 16 + c) * 512 + kt * 32 + g * 8);
      bf16x8 b[4];
#pragma unroll
      for (int nt = 0; nt < 4; ++nt) {
        int T = nt * 16 + c;
        b[nt] = *(const bf16x8*)(hb + SWZ(T, T * 512 + ko));
      }
#pragma unroll
      for (int nt = 0; nt < 4; ++nt)
        acc[nt] = mfma16(a, b[nt], acc[nt]);
    }
    float4 b4 = *(const float4*)(b2 + 512 + hh * 32 + mh * 16 + g * 4);
#pragma unroll
    for (int nt = 0; nt < 4; ++nt)
#pragma unroll
      for (int r = 0; r < 4; ++r)
        vreg[nt][r] = (bf16_t)(acc[nt][r] + ((const float*)&b4)[r]);
  }
  // round q (scaled)
  {
    f32x4 acc[4] = {};
#pragma unroll
    for (int kt = 0; kt < 16; ++kt) {
      const char* hb = (kt < 8) ? rB : rA;
      const int ko = (kt & 7) * 64 + g * 16;
      bf16x8 a = *(const bf16x8*)(w2t + (size_t)(hh * 32 + mh * 16 + c) * 512 + kt * 32 + g * 8);
      bf16x8 b[4];
#pragma unroll
      for (int nt = 0; nt < 4; ++nt) {
        int T = nt * 16 + c;
        b[nt] = *(const bf16x8*)(hb + SWZ(T, T * 512 + ko));
      }
#pragma unroll
      for (int nt = 0; nt < 4; ++nt)
        acc[nt] = mfma16(a, b[nt], acc[nt]);
    }
    float4 b4 = *(const float4*)(b2 + hh * 32 + mh * 16 + g * 4);
#pragma unroll
    for (int nt = 0; nt < 4; ++nt)
#pragma unroll
      for (int r = 0; r < 4; ++r)
        qreg[nt][r] = (bf16_t)((acc[nt][r] + ((const float*)&b4)[r]) * 0.17677669529663687f);
  }
  // round k
  {
    f32x4 acc[4] = {};
#pragma unroll
    for (int kt = 0; kt < 16; ++kt) {
      const char* hb = (kt < 8) ? rB : rA;
      const int ko = (kt & 7) * 64 + g * 16;
      bf16x8 a = *(const bf16x8*)(w2t + (size_t)(256 + hh * 32 + mh * 16 + c) * 512 + kt * 32 + g * 8);
      bf16x8 b[4];
#pragma unroll
      for (int nt = 0; nt < 4; ++nt) {
        int T = nt * 16 + c;
        b[nt] = *(const bf16x8*)(hb + SWZ(T, T * 512 + ko));
      }
#pragma unroll
      for (int nt = 0; nt < 4; ++nt)
        acc[nt] = mfma16(a, b[nt], acc[nt]);
    }
    float4 b4 = *(const float4*)(b2 + 256 + hh * 32 + mh * 16 + g * 4);
#pragma unroll
    for (int nt = 0; nt < 4; ++nt)
#pragma unroll
      for (int r = 0; r < 4; ++r)
        kreg[nt][r] = (bf16_t)(acc[nt][r] + ((const float*)&b4)[r]);
  }
  __syncthreads();  // S2: all h reads done -> [0,64K) reusable; part dead

  // ---- stage q,k (all 8 heads into [0,64K)) and vt (into [64K,96K)) ----
  {
    char* qb = sm + hh * 8192;
    const int d0 = mh * 16 + g * 4;
#pragma unroll
    for (int nt = 0; nt < 4; ++nt) {
      int T = nt * 16 + c;
      *(bf16x4*)(qb + SWZ(T, T * 64 + d0 * 2)) = qreg[nt];
      *(bf16x4*)(qb + 4096 + SWZ(T, T * 64 + d0 * 2)) = kreg[nt];
    }
    char* vs = sm + 65536 + hh * 4096;
#pragma unroll
    for (int nt = 0; nt < 4; ++nt) {
      int T = nt * 16 + c;
#pragma unroll
      for (int r = 0; r < 4; ++r) {
        int d = d0 + r;
        *(bf16_t*)(vs + SWZ(d, d * 128 + T * 2)) = vreg[nt][r];
      }
    }
  }
  __syncthreads();  // S3: q/k/vt visible

  // ---- attention: 16 waves = 8 heads x 2 row-halves, single pass ----
  const int h8 = wave & 7, rowbase = (wave >> 3) * 32;
  char* qb = sm + h8 * 8192;
  char* vslot = sm + 65536 + h8 * 4096;
  const float* btab = bt + h8 * 4096;  // [64][64] f32

  bf16x8 aq[2], bk[4];
#pragma unroll
  for (int mt = 0; mt < 2; ++mt) {
    int t = rowbase + mt * 16 + c;
    aq[mt] = *(const bf16x8*)(qb + SWZ(t, t * 64 + g * 16));
  }
#pragma unroll
  for (int nt = 0; nt < 4; ++nt) {
    int t = nt * 16 + c;
    bk[nt] = *(const bf16x8*)(qb + 4096 + SWZ(t, t * 64 + g * 16));
  }
  float p[2][4][4];
#pragma unroll
  for (int mt = 0; mt < 2; ++mt)
#pragma unroll
    for (int nt = 0; nt < 4; ++nt) {
      f32x4 z = {0.f, 0.f, 0.f, 0.f};
      f32x4 s4 = mfma16(aq[mt], bk[nt], z);
#pragma unroll
      for (int r = 0; r < 4; ++r) {
        int i = rowbase + mt * 16 + g * 4 + r, j = nt * 16 + c;
        p[mt][nt][r] = s4[r] + btab[i * 64 + j];
      }
    }
#pragma unroll
  for (int mt = 0; mt < 2; ++mt)
#pragma unroll
    for (int r = 0; r < 4; ++r) {
      float mx = fmaxf(fmaxf(p[mt][0][r], p[mt][1][r]), fmaxf(p[mt][2][r], p[mt][3][r]));
#pragma unroll
      for (int m = 1; m < 16; m <<= 1) mx = fmaxf(mx, __shfl_xor(mx, m, 64));
      float sum = 0.f;
#pragma unroll
      for (int nt = 0; nt < 4; ++nt) {
        float e = __expf(p[mt][nt][r] - mx);
        p[mt][nt][r] = e; sum += e;
      }
#pragma unroll
      for (int m = 1; m < 16; m <<= 1) sum += __shfl_xor(sum, m, 64);
      float rinv = 1.f / sum;
#pragma unroll
      for (int nt = 0; nt < 4; ++nt) p[mt][nt][r] *= rinv;
    }
  __syncthreads();  // S4: all q/k reads done before P overlays qk slots

#pragma unroll
  for (int mt = 0; mt < 2; ++mt)
#pragma unroll
    for (int nt = 0; nt < 4; ++nt)
#pragma unroll
      for (int r = 0; r < 4; ++r) {
        int i = rowbase + mt * 16 + g * 4 + r, j = nt * 16 + c;
        *(bf16_t*)(qb + SWZ(i, i * 128 + j * 2)) = (bf16_t)p[mt][nt][r];
      }
  asm volatile("s_waitcnt lgkmcnt(0)" ::: "memory");  // in-wave P write->read (own rows only)
  f32x4 oacc[2][2] = {};
#pragma unroll
  for (int kp = 0; kp < 2; ++kp) {
    bf16x8 ap[2], bv[2];
#pragma unroll
    for (int mt = 0; mt < 2; ++mt) {
      int t = rowbase + mt * 16 + c;
      ap[mt] = *(const bf16x8*)(qb + SWZ(t, t * 128 + kp * 64 + g * 16));
    }
#pragma unroll
    for (int nt = 0; nt < 2; ++nt) {
      int d = nt * 16 + c;
      bv[nt] = *(const bf16x8*)(vslot + SWZ(d, d * 128 + kp * 64 + g * 16));
    }
#pragma unroll
    for (int mt = 0; mt < 2; ++mt)
#pragma unroll
      for (int nt = 0; nt < 2; ++nt)
        oacc[mt][nt] = mfma16(ap[mt], bv[nt], oacc[mt][nt]);
  }
#pragma unroll
  for (int mt = 0; mt < 2; ++mt)
#pragma unroll
    for (int nt = 0; nt < 2; ++nt)
#pragma unroll
      for (int r = 0; r < 4; ++r) {
        int T = rowbase + mt * 16 + g * 4 + r;
        ao[(size_t)(win * 64 + T) * 256 + h8 * 32 + nt * 16 + c] = (bf16_t)oacc[mt][nt][r];
      }
}

// ========== K_B: ao -> GEMM3+LN+GELU -> h2(LDS) -> GEMM4 -> out ==========
__global__ __launch_bounds__(1024, 1) void g3g4_kernel(
    const bf16_t* __restrict__ ao,
    const bf16_t* __restrict__ wp1t, const float* __restrict__ bp1,
    const float* __restrict__ gp, const float* __restrict__ bep,
    const bf16_t* __restrict__ wp2t, const float* __restrict__ bp2,
    float* __restrict__ out)
{
  __shared__ __align__(16) char sm[73728];
  char* rA = sm;
  char* rB = sm + 32768;
  float2* part = (float2*)(sm + 65536);
  const int tid = threadIdx.x;
  const int wave = tid >> 6, lane = tid & 63;
  const int g = lane >> 4, c = lane & 15;
  const int win = blockIdx.x;

  // ---- stage ao (coalesced) ----
  const bf16_t* aow = ao + (size_t)win * 16384;
#pragma unroll
  for (int it = 0; it < 2; ++it) {
    int e = it * 8192 + tid * 8;
    bf16x8 v = *(const bf16x8*)(aow + e);
    int row = e >> 8, col = e & 255;
    *(bf16x8*)(rA + SWZ(row, row * 512 + col * 2)) = v;
  }
  __syncthreads();
  gemmT_ln_gelu16(rA, wp1t, bp1, gp, bep, (wave < 8) ? rB : rA, (wave & 7) * 32,
                  part, wave, g, c);
  __syncthreads();  // h2 complete (rB = feats 0-255, rA = feats 256-511)

  // ---- GEMM4: out = h2 @ wp2 + bp2 (16 waves x 16 out-feats) ----
  f32x4 acc[4] = {};
#pragma unroll
  for (int kt = 0; kt < 16; ++kt) {
    const char* hb = (kt < 8) ? rB : rA;
    const int ko = (kt & 7) * 64 + g * 16;
    bf16x8 a = *(const bf16x8*)(wp2t + (size_t)(wave * 16 + c) * 512 + kt * 32 + g * 8);
    bf16x8 b[4];
#pragma unroll
    for (int nt = 0; nt < 4; ++nt) {
      int T = nt * 16 + c;
      b[nt] = *(const bf16x8*)(hb + SWZ(T, T * 512 + ko));
    }
#pragma unroll
    for (int nt = 0; nt < 4; ++nt)
      acc[nt] = mfma16(a, b[nt], acc[nt]);
  }
  float* ow = out + (size_t)win * 16384;
  float4 b4 = *(const float4*)(bp2 + wave * 16 + g * 4);
#pragma unroll
  for (int nt = 0; nt < 4; ++nt) {
    int T = nt * 16 + c;
    f32x4 o4;
#pragma unroll
    for (int r = 0; r < 4; ++r) o4[r] = acc[nt][r] + ((const float*)&b4)[r];
    *(f32x4*)(ow + T * 256 + wave * 16 + g * 4) = o4;
  }
}

extern "C" void kernel_launch(void* const* d_in, const int* in_sizes, int n_in,
                              void* d_out, int out_size, void* d_ws, size_t ws_size,
                              hipStream_t stream) {
  const float* x   = (const float*)d_in[0];
  const float* w1  = (const float*)d_in[1];
  const float* b1  = (const float*)d_in[2];
  const float* g1  = (const float*)d_in[3];
  const float* be1 = (const float*)d_in[4];
  const float* w2  = (const float*)d_in[5];
  const float* b2  = (const float*)d_in[6];
  const float* rpb = (const float*)d_in[7];
  const float* wp1 = (const float*)d_in[8];
  const float* bp1 = (const float*)d_in[9];
  const float* gp  = (const float*)d_in[10];
  const float* bep = (const float*)d_in[11];
  const float* wp2 = (const float*)d_in[12];
  const float* bp2 = (const float*)d_in[13];
  float* out = (float*)d_out;
  char* ws = (char*)d_ws;
  // ws layout: transposed bf16 weights (1.5 MB) | bias table (128 KB) | ao (128 MB)
  bf16_t* w1t  = (bf16_t*)(ws + 0);          // [512][256]
  bf16_t* w2t  = (bf16_t*)(ws + 262144);     // [768][512]
  bf16_t* wp1t = (bf16_t*)(ws + 1048576);    // [512][256]
  bf16_t* wp2t = (bf16_t*)(ws + 1310720);    // [256][512]
  float*  bt   = (float*)(ws + 1572864);     // [8][64][64] f32
  bf16_t* ao   = (bf16_t*)(ws + 2097152);    // [262144][256] bf16 = 128 MB

  wtrans_kernel<<<512, 256, 0, stream>>>(w1, w1t, 8, 512, 131072);
  wtrans_kernel<<<1536, 256, 0, stream>>>(w2, w2t, 9, 768, 393216);
  wtrans_kernel<<<512, 256, 0, stream>>>(wp1, wp1t, 8, 512, 131072);
  wtrans_kernel<<<512, 256, 0, stream>>>(wp2, wp2t, 9, 256, 131072);
  biastab_kernel<<<128, 256, 0, stream>>>(rpb, bt);

  g1qa_kernel<<<4096, 1024, 0, stream>>>(x, w1t, b1, g1, be1, w2t, b2, bt, ao);
  g3g4_kernel<<<4096, 1024, 0, stream>>>(ao, wp1t, bp1, gp, bep, wp2t, bp2, out);
}

// Round 5
// 1104.150 us; speedup vs baseline: 1.0874x; 1.0179x over previous
//
#include <hip/hip_runtime.h>

// 2-stage fused pipeline, ONE 64-token window per 1024-thread block (16 waves).
// Round-4 finding: time invariant to occupancy (24->47%) and per-wave work ->
// latency/LDS-throughput bound, NOT issue bound. Dominant LDS consumer was
// G2's 3 broadcast rounds (every wave reads the full 64KB h tile per round =
// 3 MB/window). Round 5: fuse v,q,k into ONE pass over h (12 MFMA per 4
// h-reads) -> 1 MB/window LDS reads, 1/3 the G2 phase chain.
//   K_A: x -> GEMM1+LN+GELU -> h(LDS) -> fused GEMM2(qkv) -> attn -> ao (bf16)
//   K_B: ao -> GEMM3+LN+GELU -> h2(LDS) -> GEMM4 -> out (f32)
// K_A LDS (96 KB):
//   [0,64K)   rA/rB: x-tile -> h -> (after S2) qk slots, 8 heads x 8K (q|k),
//             P overlays qk per head during PV
//   [64K,96K) vt 8 heads x 4K (staged after S2); LN partials early (dead by S2)

typedef __bf16 bf16_t;
typedef __bf16 bf16x8 __attribute__((ext_vector_type(8)));
typedef __bf16 bf16x4 __attribute__((ext_vector_type(4)));
typedef float f32x4 __attribute__((ext_vector_type(4)));

__device__ __forceinline__ f32x4 mfma16(bf16x8 a, bf16x8 b, f32x4 acc) {
  return __builtin_amdgcn_mfma_f32_16x16x32_bf16(a, b, acc, 0, 0, 0);
}

// XOR-swizzle: fold row's low 3 bits into byte-address bits [6:4].
#define SWZ(row, byteoff) ((byteoff) ^ (((row) & 7) << 4))

// cheap GELU: tanh form, max |err| vs exact erf-GELU ~3e-4.
__device__ __forceinline__ float gelu_f(float v) {
  float e = __expf(v * (1.59576912f + 0.07135482f * v * v));
  return v - v * __builtin_amdgcn_rcpf(1.0f + e);
}

// transpose + convert: dst[n*K + k] = bf16(src[k*N + n])
__global__ void wtrans_kernel(const float* __restrict__ src, bf16_t* __restrict__ dst,
                              int kshift, int N, int total) {
  int i = blockIdx.x * 256 + threadIdx.x;
  if (i >= total) return;
  int K = 1 << kshift;
  int k = i & (K - 1);
  int n = i >> kshift;
  dst[i] = (bf16_t)src[(size_t)k * N + n];
}

// expand rpb[(2*8-1)^2][8] -> bt[8][64][64] f32 (window-invariant)
__global__ void biastab_kernel(const float* __restrict__ rpb, float* __restrict__ bt) {
  int e = blockIdx.x * 256 + threadIdx.x;  // 32768 total
  int hd = e >> 12, i = (e >> 6) & 63, j = e & 63;
  int idx = ((i >> 3) - (j >> 3) + 7) * 15 + ((i & 7) - (j & 7) + 7);
  bt[e] = rpb[idx * 8 + hd];
}

// 16-wave transposed GEMM (C^T = W * A^T) + bias + LayerNorm(512) + cheap GELU.
// Each wave produces 32 output features. bsrc: [64 tok][256 k] bf16 LDS tile
// (swizzled, 512 B rows). wt: [512 feat][256 k] bf16 global.
// Output staged to h-halves in LDS. Contains ONE __syncthreads.
__device__ __forceinline__ void gemmT_ln_gelu16(
    const char* bsrc, const bf16_t* __restrict__ wt,
    const float* __restrict__ bias, const float* __restrict__ gamma,
    const float* __restrict__ beta,
    char* dst, int flb, float2* part, int wave, int g, int c)
{
  f32x4 acc[2][4] = {};
#pragma unroll
  for (int kt = 0; kt < 8; ++kt) {
    bf16x8 a[2], b[4];
#pragma unroll
    for (int mt = 0; mt < 2; ++mt)
      a[mt] = *(const bf16x8*)(wt + (size_t)(wave * 32 + mt * 16 + c) * 256 + kt * 32 + g * 8);
#pragma unroll
    for (int nt = 0; nt < 4; ++nt) {
      int T = nt * 16 + c;
      b[nt] = *(const bf16x8*)(bsrc + SWZ(T, T * 512 + kt * 64 + g * 16));
    }
#pragma unroll
    for (int mt = 0; mt < 2; ++mt)
#pragma unroll
      for (int nt = 0; nt < 4; ++nt)
        acc[mt][nt] = mfma16(a[mt], b[nt], acc[mt][nt]);
  }
  float s[4] = {0.f, 0.f, 0.f, 0.f}, ss[4] = {0.f, 0.f, 0.f, 0.f};
#pragma unroll
  for (int mt = 0; mt < 2; ++mt) {
    float4 b4 = *(const float4*)(bias + wave * 32 + mt * 16 + g * 4);
#pragma unroll
    for (int nt = 0; nt < 4; ++nt)
#pragma unroll
      for (int r = 0; r < 4; ++r) {
        float v = acc[mt][nt][r] + ((const float*)&b4)[r];
        acc[mt][nt][r] = v;
        s[nt] += v;
        ss[nt] += v * v;
      }
  }
#pragma unroll
  for (int nt = 0; nt < 4; ++nt) {
    float sv = s[nt], ssv = ss[nt];
    sv += __shfl_xor(sv, 16, 64); ssv += __shfl_xor(ssv, 16, 64);
    sv += __shfl_xor(sv, 32, 64); ssv += __shfl_xor(ssv, 32, 64);
    if (g == 0) part[wave * 64 + nt * 16 + c] = make_float2(sv, ssv);
  }
  __syncthreads();
#pragma unroll
  for (int nt = 0; nt < 4; ++nt) {
    float sv = 0.f, ssv = 0.f;
#pragma unroll
    for (int w = 0; w < 16; ++w) {
      float2 p2 = part[w * 64 + nt * 16 + c];
      sv += p2.x; ssv += p2.y;
    }
    float m = sv * (1.f / 512.f);
    float rstd = rsqrtf(ssv * (1.f / 512.f) - m * m + 1e-5f);
#pragma unroll
    for (int mt = 0; mt < 2; ++mt)
#pragma unroll
      for (int r = 0; r < 4; ++r)
        acc[mt][nt][r] = (acc[mt][nt][r] - m) * rstd;
  }
#pragma unroll
  for (int mt = 0; mt < 2; ++mt) {
    float4 g4 = *(const float4*)(gamma + wave * 32 + mt * 16 + g * 4);
    float4 be4 = *(const float4*)(beta + wave * 32 + mt * 16 + g * 4);
    int f0 = flb + mt * 16 + g * 4;
#pragma unroll
    for (int nt = 0; nt < 4; ++nt) {
      int T = nt * 16 + c;
      bf16x4 h4;
#pragma unroll
      for (int r = 0; r < 4; ++r) {
        float v = acc[mt][nt][r] * ((const float*)&g4)[r] + ((const float*)&be4)[r];
        h4[r] = (bf16_t)gelu_f(v);
      }
      *(bf16x4*)(dst + SWZ(T, T * 512 + f0 * 2)) = h4;
    }
  }
}

// ========== K_A: x -> GEMM1+LN+GELU -> h(LDS) -> fused G2 -> attn -> ao ==========
__global__ __launch_bounds__(1024, 1) void g1qa_kernel(
    const float* __restrict__ x,
    const bf16_t* __restrict__ w1t, const float* __restrict__ b1,
    const float* __restrict__ gamma1, const float* __restrict__ beta1,
    const bf16_t* __restrict__ w2t, const float* __restrict__ b2,
    const float* __restrict__ bt,
    bf16_t* __restrict__ ao)
{
  __shared__ __align__(16) char sm[98304];
  char* rA = sm;
  char* rB = sm + 32768;
  float2* part = (float2*)(sm + 65536);  // dead before vt is staged (2 barriers apart)
  const int tid = threadIdx.x;
  const int wave = tid >> 6, lane = tid & 63;
  const int g = lane >> 4, c = lane & 15;
  const int win = blockIdx.x;

  // ---- stage x (f32 -> bf16 tile, coalesced) ----
  const float* xw = x + (size_t)win * 16384;
#pragma unroll
  for (int it = 0; it < 4; ++it) {
    int e = it * 4096 + tid * 4;
    float4 v = *(const float4*)(xw + e);
    int row = e >> 8, col = e & 255;
    bf16x4 t4;
    t4[0] = (bf16_t)v.x; t4[1] = (bf16_t)v.y; t4[2] = (bf16_t)v.z; t4[3] = (bf16_t)v.w;
    *(bf16x4*)(rA + SWZ(row, row * 512 + col * 2)) = t4;
  }
  __syncthreads();
  gemmT_ln_gelu16(rA, w1t, b1, gamma1, beta1, (wave < 8) ? rB : rA, (wave & 7) * 32,
                  part, wave, g, c);
  __syncthreads();  // S1: h complete (rB = feats 0-255, rA = feats 256-511)

  // ---- fused G2: 16 waves = 8 heads x 2 feat-halves; ONE pass over h
  //      computes v, q, k together (12 MFMA per 4 h-reads) ----
  const int hh = wave >> 1, mh = wave & 1;
  bf16x4 vreg[4], qreg[4], kreg[4];
  {
    f32x4 accv[4] = {}, accq[4] = {}, acck[4] = {};
    const bf16_t* wq = w2t + (size_t)(hh * 32 + mh * 16 + c) * 512;
    const bf16_t* wk = wq + (size_t)256 * 512;
    const bf16_t* wv = wq + (size_t)512 * 512;
#pragma unroll
    for (int kt = 0; kt < 16; ++kt) {
      const char* hb = (kt < 8) ? rB : rA;
      const int ko = (kt & 7) * 64 + g * 16;
      bf16x8 av = *(const bf16x8*)(wv + kt * 32 + g * 8);
      bf16x8 aq = *(const bf16x8*)(wq + kt * 32 + g * 8);
      bf16x8 ak = *(const bf16x8*)(wk + kt * 32 + g * 8);
      bf16x8 b[4];
#pragma unroll
      for (int nt = 0; nt < 4; ++nt) {
        int T = nt * 16 + c;
        b[nt] = *(const bf16x8*)(hb + SWZ(T, T * 512 + ko));
      }
#pragma unroll
      for (int nt = 0; nt < 4; ++nt) {
        accv[nt] = mfma16(av, b[nt], accv[nt]);
        accq[nt] = mfma16(aq, b[nt], accq[nt]);
        acck[nt] = mfma16(ak, b[nt], acck[nt]);
      }
    }
    float4 bv4 = *(const float4*)(b2 + 512 + hh * 32 + mh * 16 + g * 4);
    float4 bq4 = *(const float4*)(b2 + hh * 32 + mh * 16 + g * 4);
    float4 bk4 = *(const float4*)(b2 + 256 + hh * 32 + mh * 16 + g * 4);
#pragma unroll
    for (int nt = 0; nt < 4; ++nt)
#pragma unroll
      for (int r = 0; r < 4; ++r) {
        vreg[nt][r] = (bf16_t)(accv[nt][r] + ((const float*)&bv4)[r]);
        qreg[nt][r] = (bf16_t)((accq[nt][r] + ((const float*)&bq4)[r]) * 0.17677669529663687f);
        kreg[nt][r] = (bf16_t)(acck[nt][r] + ((const float*)&bk4)[r]);
      }
  }
  __syncthreads();  // S2: all h reads done -> [0,64K) reusable; part dead

  // ---- stage q,k (all 8 heads into [0,64K)) and vt (into [64K,96K)) ----
  {
    char* qb = sm + hh * 8192;
    const int d0 = mh * 16 + g * 4;
#pragma unroll
    for (int nt = 0; nt < 4; ++nt) {
      int T = nt * 16 + c;
      *(bf16x4*)(qb + SWZ(T, T * 64 + d0 * 2)) = qreg[nt];
      *(bf16x4*)(qb + 4096 + SWZ(T, T * 64 + d0 * 2)) = kreg[nt];
    }
    char* vs = sm + 65536 + hh * 4096;
#pragma unroll
    for (int nt = 0; nt < 4; ++nt) {
      int T = nt * 16 + c;
#pragma unroll
      for (int r = 0; r < 4; ++r) {
        int d = d0 + r;
        *(bf16_t*)(vs + SWZ(d, d * 128 + T * 2)) = vreg[nt][r];
      }
    }
  }
  __syncthreads();  // S3: q/k/vt visible

  // ---- attention: 16 waves = 8 heads x 2 row-halves, single pass ----
  const int h8 = wave & 7, rowbase = (wave >> 3) * 32;
  char* qb = sm + h8 * 8192;
  char* vslot = sm + 65536 + h8 * 4096;
  const float* btab = bt + h8 * 4096;  // [64][64] f32

  bf16x8 aq[2], bk[4];
#pragma unroll
  for (int mt = 0; mt < 2; ++mt) {
    int t = rowbase + mt * 16 + c;
    aq[mt] = *(const bf16x8*)(qb + SWZ(t, t * 64 + g * 16));
  }
#pragma unroll
  for (int nt = 0; nt < 4; ++nt) {
    int t = nt * 16 + c;
    bk[nt] = *(const bf16x8*)(qb + 4096 + SWZ(t, t * 64 + g * 16));
  }
  float p[2][4][4];
#pragma unroll
  for (int mt = 0; mt < 2; ++mt)
#pragma unroll
    for (int nt = 0; nt < 4; ++nt) {
      f32x4 z = {0.f, 0.f, 0.f, 0.f};
      f32x4 s4 = mfma16(aq[mt], bk[nt], z);
#pragma unroll
      for (int r = 0; r < 4; ++r) {
        int i = rowbase + mt * 16 + g * 4 + r, j = nt * 16 + c;
        p[mt][nt][r] = s4[r] + btab[i * 64 + j];
      }
    }
#pragma unroll
  for (int mt = 0; mt < 2; ++mt)
#pragma unroll
    for (int r = 0; r < 4; ++r) {
      float mx = fmaxf(fmaxf(p[mt][0][r], p[mt][1][r]), fmaxf(p[mt][2][r], p[mt][3][r]));
#pragma unroll
      for (int m = 1; m < 16; m <<= 1) mx = fmaxf(mx, __shfl_xor(mx, m, 64));
      float sum = 0.f;
#pragma unroll
      for (int nt = 0; nt < 4; ++nt) {
        float e = __expf(p[mt][nt][r] - mx);
        p[mt][nt][r] = e; sum += e;
      }
#pragma unroll
      for (int m = 1; m < 16; m <<= 1) sum += __shfl_xor(sum, m, 64);
      float rinv = 1.f / sum;
#pragma unroll
      for (int nt = 0; nt < 4; ++nt) p[mt][nt][r] *= rinv;
    }
  __syncthreads();  // S4: all q/k reads done before P overlays qk slots

#pragma unroll
  for (int mt = 0; mt < 2; ++mt)
#pragma unroll
    for (int nt = 0; nt < 4; ++nt)
#pragma unroll
      for (int r = 0; r < 4; ++r) {
        int i = rowbase + mt * 16 + g * 4 + r, j = nt * 16 + c;
        *(bf16_t*)(qb + SWZ(i, i * 128 + j * 2)) = (bf16_t)p[mt][nt][r];
      }
  asm volatile("s_waitcnt lgkmcnt(0)" ::: "memory");  // in-wave P write->read (own rows only)
  f32x4 oacc[2][2] = {};
#pragma unroll
  for (int kp = 0; kp < 2; ++kp) {
    bf16x8 ap[2], bv[2];
#pragma unroll
    for (int mt = 0; mt < 2; ++mt) {
      int t = rowbase + mt * 16 + c;
      ap[mt] = *(const bf16x8*)(qb + SWZ(t, t * 128 + kp * 64 + g * 16));
    }
#pragma unroll
    for (int nt = 0; nt < 2; ++nt) {
      int d = nt * 16 + c;
      bv[nt] = *(const bf16x8*)(vslot + SWZ(d, d * 128 + kp * 64 + g * 16));
    }
#pragma unroll
    for (int mt = 0; mt < 2; ++mt)
#pragma unroll
      for (int nt = 0; nt < 2; ++nt)
        oacc[mt][nt] = mfma16(ap[mt], bv[nt], oacc[mt][nt]);
  }
#pragma unroll
  for (int mt = 0; mt < 2; ++mt)
#pragma unroll
    for (int nt = 0; nt < 2; ++nt)
#pragma unroll
      for (int r = 0; r < 4; ++r) {
        int T = rowbase + mt * 16 + g * 4 + r;
        ao[(size_t)(win * 64 + T) * 256 + h8 * 32 + nt * 16 + c] = (bf16_t)oacc[mt][nt][r];
      }
}

// ========== K_B: ao -> GEMM3+LN+GELU -> h2(LDS) -> GEMM4 -> out ==========
__global__ __launch_bounds__(1024, 1) void g3g4_kernel(
    const bf16_t* __restrict__ ao,
    const bf16_t* __restrict__ wp1t, const float* __restrict__ bp1,
    const float* __restrict__ gp, const float* __restrict__ bep,
    const bf16_t* __restrict__ wp2t, const float* __restrict__ bp2,
    float* __restrict__ out)
{
  __shared__ __align__(16) char sm[73728];
  char* rA = sm;
  char* rB = sm + 32768;
  float2* part = (float2*)(sm + 65536);
  const int tid = threadIdx.x;
  const int wave = tid >> 6, lane = tid & 63;
  const int g = lane >> 4, c = lane & 15;
  const int win = blockIdx.x;

  // ---- stage ao (coalesced) ----
  const bf16_t* aow = ao + (size_t)win * 16384;
#pragma unroll
  for (int it = 0; it < 2; ++it) {
    int e = it * 8192 + tid * 8;
    bf16x8 v = *(const bf16x8*)(aow + e);
    int row = e >> 8, col = e & 255;
    *(bf16x8*)(rA + SWZ(row, row * 512 + col * 2)) = v;
  }
  __syncthreads();
  gemmT_ln_gelu16(rA, wp1t, bp1, gp, bep, (wave < 8) ? rB : rA, (wave & 7) * 32,
                  part, wave, g, c);
  __syncthreads();  // h2 complete (rB = feats 0-255, rA = feats 256-511)

  // ---- GEMM4: out = h2 @ wp2 + bp2 (16 waves x 16 out-feats) ----
  f32x4 acc[4] = {};
#pragma unroll
  for (int kt = 0; kt < 16; ++kt) {
    const char* hb = (kt < 8) ? rB : rA;
    const int ko = (kt & 7) * 64 + g * 16;
    bf16x8 a = *(const bf16x8*)(wp2t + (size_t)(wave * 16 + c) * 512 + kt * 32 + g * 8);
    bf16x8 b[4];
#pragma unroll
    for (int nt = 0; nt < 4; ++nt) {
      int T = nt * 16 + c;
      b[nt] = *(const bf16x8*)(hb + SWZ(T, T * 512 + ko));
    }
#pragma unroll
    for (int nt = 0; nt < 4; ++nt)
      acc[nt] = mfma16(a, b[nt], acc[nt]);
  }
  float* ow = out + (size_t)win * 16384;
  float4 b4 = *(const float4*)(bp2 + wave * 16 + g * 4);
#pragma unroll
  for (int nt = 0; nt < 4; ++nt) {
    int T = nt * 16 + c;
    f32x4 o4;
#pragma unroll
    for (int r = 0; r < 4; ++r) o4[r] = acc[nt][r] + ((const float*)&b4)[r];
    *(f32x4*)(ow + T * 256 + wave * 16 + g * 4) = o4;
  }
}

extern "C" void kernel_launch(void* const* d_in, const int* in_sizes, int n_in,
                              void* d_out, int out_size, void* d_ws, size_t ws_size,
                              hipStream_t stream) {
  const float* x   = (const float*)d_in[0];
  const float* w1  = (const float*)d_in[1];
  const float* b1  = (const float*)d_in[2];
  const float* g1  = (const float*)d_in[3];
  const float* be1 = (const float*)d_in[4];
  const float* w2  = (const float*)d_in[5];
  const float* b2  = (const float*)d_in[6];
  const float* rpb = (const float*)d_in[7];
  const float* wp1 = (const float*)d_in[8];
  const float* bp1 = (const float*)d_in[9];
  const float* gp  = (const float*)d_in[10];
  const float* bep = (const float*)d_in[11];
  const float* wp2 = (const float*)d_in[12];
  const float* bp2 = (const float*)d_in[13];
  float* out = (float*)d_out;
  char* ws = (char*)d_ws;
  // ws layout: transposed bf16 weights (1.5 MB) | bias table (128 KB) | ao (128 MB)
  bf16_t* w1t  = (bf16_t*)(ws + 0);          // [512][256]
  bf16_t* w2t  = (bf16_t*)(ws + 262144);     // [768][512]
  bf16_t* wp1t = (bf16_t*)(ws + 1048576);    // [512][256]
  bf16_t* wp2t = (bf16_t*)(ws + 1310720);    // [256][512]
  float*  bt   = (float*)(ws + 1572864);     // [8][64][64] f32
  bf16_t* ao   = (bf16_t*)(ws + 2097152);    // [262144][256] bf16 = 128 MB

  wtrans_kernel<<<512, 256, 0, stream>>>(w1, w1t, 8, 512, 131072);
  wtrans_kernel<<<1536, 256, 0, stream>>>(w2, w2t, 9, 768, 393216);
  wtrans_kernel<<<512, 256, 0, stream>>>(wp1, wp1t, 8, 512, 131072);
  wtrans_kernel<<<512, 256, 0, stream>>>(wp2, wp2t, 9, 256, 131072);
  biastab_kernel<<<128, 256, 0, stream>>>(rpb, bt);

  g1qa_kernel<<<4096, 1024, 0, stream>>>(x, w1t, b1, g1, be1, w2t, b2, bt, ao);
  g3g4_kernel<<<4096, 1024, 0, stream>>>(ao, wp1t, bp1, gp, bep, wp2t, bp2, out);
}